// Round 1
// 1745.170 us; speedup vs baseline: 1.0521x; 1.0521x over previous
//
#include <hip/hip_runtime.h>
#include <cstdint>
#include <cstddef>

constexpr int Lc = 2, Ec = 8, Hc = 1024, Ic = 2048, Tc = 2048;

typedef __bf16 bf16x8 __attribute__((ext_vector_type(8)));
typedef float f32x4 __attribute__((ext_vector_type(4)));

__device__ __forceinline__ unsigned short f2bf(float f) {
  unsigned u = __builtin_bit_cast(unsigned, f);
  u = (u + 0x7fffu + ((u >> 16) & 1u)) >> 16;
  return (unsigned short)u;
}
__device__ __forceinline__ float bf2f(unsigned short h) {
  unsigned u = (unsigned)h << 16;
  return __builtin_bit_cast(float, u);
}
__device__ __forceinline__ bf16x8 ldfrag(const unsigned short* p) {
  return __builtin_bit_cast(bf16x8, *(const uint4*)p);
}

// ---------------- router: logits[t][e] = sum_h x[t][h] * rw[h][e] (fp32) ----------------
__global__ void router_kernel(const float* __restrict__ x, const float* __restrict__ rw,
                              float* __restrict__ logits) {
  const int t = blockIdx.x;
  const int tid = threadIdx.x;
  float acc[Ec];
#pragma unroll
  for (int e = 0; e < Ec; ++e) acc[e] = 0.f;
  const float* xr = x + (size_t)t * Hc;
  for (int h = tid; h < Hc; h += 256) {
    const float xv = xr[h];
    const float* w = rw + (size_t)h * Ec;
#pragma unroll
    for (int e = 0; e < Ec; ++e) acc[e] += xv * w[e];
  }
  __shared__ float red[256][Ec];
#pragma unroll
  for (int e = 0; e < Ec; ++e) red[tid][e] = acc[e];
  __syncthreads();
  for (int s = 128; s > 0; s >>= 1) {
    if (tid < s) {
#pragma unroll
      for (int e = 0; e < Ec; ++e) red[tid][e] += red[tid + s][e];
    }
    __syncthreads();
  }
  if (tid < Ec) logits[(size_t)t * Ec + tid] = red[0][tid];
}

// ---------------- top-2 + normalized weights + per-expert append ----------------
__global__ void topk_kernel(const float* __restrict__ logits, int* __restrict__ cnt,
                            int* __restrict__ tokList, float* __restrict__ wList) {
  const int t = blockIdx.x * blockDim.x + threadIdx.x;
  if (t >= Tc) return;
  float l[Ec];
#pragma unroll
  for (int e = 0; e < Ec; ++e) l[e] = logits[(size_t)t * Ec + e];
  float b0 = -3.4e38f, b1 = -3.4e38f;
  int i0 = 0, i1 = 0;
#pragma unroll
  for (int e = 0; e < Ec; ++e) {
    if (l[e] > b0) { b1 = b0; i1 = i0; b0 = l[e]; i0 = e; }
    else if (l[e] > b1) { b1 = l[e]; i1 = e; }
  }
  const float w0 = 1.f / (1.f + expf(b1 - b0));
  const float w1 = 1.f - w0;
  int p0 = atomicAdd(&cnt[i0], 1);
  tokList[i0 * Tc + p0] = t;
  wList[i0 * Tc + p0] = w0;
  int p1 = atomicAdd(&cnt[i1], 1);
  tokList[i1 * Tc + p1] = t;
  wList[i1 * Tc + p1] = w1;
}

__global__ void offsets_kernel(const int* __restrict__ cnt, int* __restrict__ off) {
  if (threadIdx.x == 0) {
    int s = 0;
    for (int e = 0; e < Ec; ++e) { off[e] = s; s += cnt[e]; }
  }
}

// ---------------- fp32 -> (hi,lo) bf16 split for activations ----------------
__global__ void convert_kernel(const float* __restrict__ x, unsigned short* __restrict__ xh,
                               unsigned short* __restrict__ xl) {
  const int i = blockIdx.x * 256 + threadIdx.x;
  const float v = x[i];
  const unsigned short h = f2bf(v);
  xh[i] = h;
  xl[i] = f2bf(v - bf2f(h));
}

// ---------------- weight transpose+convert: fp32 [E][K][N] -> bf16 hi(/lo) [E][N][K] ----------------
template <bool SPLIT>
__global__ __launch_bounds__(256) void wconv_kernel(const float* __restrict__ src,
                                                    unsigned short* __restrict__ dh,
                                                    unsigned short* __restrict__ dl,
                                                    int K, int N) {
  const int e = blockIdx.z;
  const int n0 = blockIdx.x * 64;
  const int k0 = blockIdx.y * 64;
  src += (size_t)e * K * N;
  dh += (size_t)e * N * K;
  if constexpr (SPLIT) dl += (size_t)e * N * K;

  __shared__ unsigned short lh[64][66];
  __shared__ unsigned short ll[SPLIT ? 64 : 1][66];
  const int tid = threadIdx.x;

  // read 64x64 fp32 tile, coalesced along N; convert in regs; store to LDS
  {
    const int r = tid >> 2, cg = (tid & 3) * 16;
    const float* sp = src + (size_t)(k0 + r) * N + n0 + cg;
#pragma unroll
    for (int i = 0; i < 16; i += 4) {
      const float4 v = *(const float4*)(sp + i);
      const float f[4] = {v.x, v.y, v.z, v.w};
#pragma unroll
      for (int j = 0; j < 4; ++j) {
        const unsigned short h = f2bf(f[j]);
        lh[r][cg + i + j] = h;
        if constexpr (SPLIT) ll[r][cg + i + j] = f2bf(f[j] - bf2f(h));
      }
    }
  }
  __syncthreads();
  // write transposed: out row = n, contiguous along K (coalesced: 4 lanes = 128B)
  {
    const int nr = tid >> 2, kg = (tid & 3) * 16;
    union { unsigned short s[16]; uint4 u[2]; } oh, ol;
#pragma unroll
    for (int i = 0; i < 16; ++i) {
      oh.s[i] = lh[kg + i][nr];
      if constexpr (SPLIT) ol.s[i] = ll[kg + i][nr];
    }
    unsigned short* dp = dh + (size_t)(n0 + nr) * K + k0 + kg;
    *(uint4*)dp = oh.u[0];
    *(uint4*)(dp + 8) = oh.u[1];
    if constexpr (SPLIT) {
      unsigned short* dq = dl + (size_t)(n0 + nr) * K + k0 + kg;
      *(uint4*)dq = ol.u[0];
      *(uint4*)(dq + 8) = ol.u[1];
    }
  }
}

// ---------------- gate_up GEMM: act[row][n] = silu(x@Wg) * (x@Wu), gathered rows ----------------
// B operands come pre-transposed/pre-converted: gwTh/gwTl are [E][2I][H] bf16.
template <bool SPLIT>
__global__ __launch_bounds__(256) void gateup_kernel(
    const unsigned short* __restrict__ xh, const unsigned short* __restrict__ xl,
    const unsigned short* __restrict__ gwTh, const unsigned short* __restrict__ gwTl,
    const int* __restrict__ cnt, const int* __restrict__ off,
    const int* __restrict__ tokList, unsigned short* __restrict__ actH,
    unsigned short* __restrict__ actL) {
  const int e = blockIdx.z;
  const int M = cnt[e];
  const int m0 = blockIdx.x * 64;
  if (m0 >= M) return;
  const int n0 = blockIdx.y * 64;
  const int tid = threadIdx.x;

  __shared__ __align__(16) unsigned short sAh[64][40];
  __shared__ __align__(16) unsigned short sAl[SPLIT ? 64 : 1][40];
  __shared__ __align__(16) unsigned short sBgh[64][40];
  __shared__ __align__(16) unsigned short sBgl[SPLIT ? 64 : 1][40];
  __shared__ __align__(16) unsigned short sBuh[64][40];
  __shared__ __align__(16) unsigned short sBul[SPLIT ? 64 : 1][40];

  const int ar = tid >> 2;
  const int ak = (tid & 3) * 8;
  int arow = m0 + ar;
  if (arow >= M) arow = M - 1;
  const size_t abase = (size_t)tokList[e * Tc + arow] * Hc + ak;
  const unsigned short* aph = xh + abase;
  const unsigned short* apl = xl + abase;

  const size_t gbase = ((size_t)e * 2 * Ic + n0 + ar) * Hc + ak;
  const unsigned short* bgh = gwTh + gbase;
  const unsigned short* buh = bgh + (size_t)Ic * Hc;
  const unsigned short* bgl = gwTl + gbase;
  const unsigned short* bul = bgl + (size_t)Ic * Hc;

  f32x4 accg[4], accu[4];
#pragma unroll
  for (int i = 0; i < 4; ++i) {
    accg[i] = f32x4{0.f, 0.f, 0.f, 0.f};
    accu[i] = f32x4{0.f, 0.f, 0.f, 0.f};
  }

  const int lane = tid & 63;
  const int wv = tid >> 6;
  const int q = lane >> 4;
  const int mr = lane & 15;
  const int nc = wv * 16 + (lane & 15);

  for (int k0 = 0; k0 < Hc; k0 += 32) {
    __syncthreads();
    *(uint4*)&sAh[ar][ak] = *(const uint4*)(aph + k0);
    *(uint4*)&sBgh[ar][ak] = *(const uint4*)(bgh + k0);
    *(uint4*)&sBuh[ar][ak] = *(const uint4*)(buh + k0);
    if constexpr (SPLIT) {
      *(uint4*)&sAl[ar][ak] = *(const uint4*)(apl + k0);
      *(uint4*)&sBgl[ar][ak] = *(const uint4*)(bgl + k0);
      *(uint4*)&sBul[ar][ak] = *(const uint4*)(bul + k0);
    }
    __syncthreads();

    bf16x8 a_h[4], a_l[4];
#pragma unroll
    for (int mt = 0; mt < 4; ++mt) {
      a_h[mt] = ldfrag(&sAh[mt * 16 + mr][q * 8]);
      if constexpr (SPLIT) a_l[mt] = ldfrag(&sAl[mt * 16 + mr][q * 8]);
    }
    const bf16x8 bghf = ldfrag(&sBgh[nc][q * 8]);
    const bf16x8 buhf = ldfrag(&sBuh[nc][q * 8]);
    bf16x8 bglf, bulf;
    if constexpr (SPLIT) {
      bglf = ldfrag(&sBgl[nc][q * 8]);
      bulf = ldfrag(&sBul[nc][q * 8]);
    }
#pragma unroll
    for (int mt = 0; mt < 4; ++mt) {
      accg[mt] = __builtin_amdgcn_mfma_f32_16x16x32_bf16(a_h[mt], bghf, accg[mt], 0, 0, 0);
      accu[mt] = __builtin_amdgcn_mfma_f32_16x16x32_bf16(a_h[mt], buhf, accu[mt], 0, 0, 0);
      if constexpr (SPLIT) {
        accg[mt] = __builtin_amdgcn_mfma_f32_16x16x32_bf16(a_h[mt], bglf, accg[mt], 0, 0, 0);
        accg[mt] = __builtin_amdgcn_mfma_f32_16x16x32_bf16(a_l[mt], bghf, accg[mt], 0, 0, 0);
        accu[mt] = __builtin_amdgcn_mfma_f32_16x16x32_bf16(a_h[mt], bulf, accu[mt], 0, 0, 0);
        accu[mt] = __builtin_amdgcn_mfma_f32_16x16x32_bf16(a_l[mt], buhf, accu[mt], 0, 0, 0);
      }
    }
  }

  const int valid = M - m0;
  const int rowbase = off[e] + m0;
#pragma unroll
  for (int mt = 0; mt < 4; ++mt) {
#pragma unroll
    for (int r = 0; r < 4; ++r) {
      const int row = mt * 16 + q * 4 + r;  // C/D: row=(lane>>4)*4+reg, col=lane&15 (m89)
      if (row < valid) {
        const float g = accg[mt][r];
        const float u = accu[mt][r];
        const float a = (g / (1.f + expf(-g))) * u;
        const size_t idx = (size_t)(rowbase + row) * Ic + (n0 + nc);
        const unsigned short h = f2bf(a);
        actH[idx] = h;
        if constexpr (SPLIT) actL[idx] = f2bf(a - bf2f(h));
      }
    }
  }
}

// ---------------- down GEMM: out[tok[r]] += w[r] * (act[r] @ Wd) ----------------
// dwTh/dwTl are pre-transposed [E][H][I] bf16.
template <bool SPLIT>
__global__ __launch_bounds__(256) void down_kernel(
    const unsigned short* __restrict__ actH, const unsigned short* __restrict__ actL,
    const unsigned short* __restrict__ dwTh, const unsigned short* __restrict__ dwTl,
    const int* __restrict__ cnt, const int* __restrict__ off,
    const int* __restrict__ tokList, const float* __restrict__ wList,
    float* __restrict__ out) {
  const int e = blockIdx.z;
  const int M = cnt[e];
  const int m0 = blockIdx.x * 64;
  if (m0 >= M) return;
  const int n0 = blockIdx.y * 64;
  const int tid = threadIdx.x;

  __shared__ __align__(16) unsigned short sAh[64][40];
  __shared__ __align__(16) unsigned short sAl[SPLIT ? 64 : 1][40];
  __shared__ __align__(16) unsigned short sBh[64][40];
  __shared__ __align__(16) unsigned short sBl[SPLIT ? 64 : 1][40];
  __shared__ int sTok[64];
  __shared__ float sW[64];

  if (tid < 64) {
    int r = m0 + tid;
    int rc = r < M ? r : M - 1;
    sTok[tid] = tokList[e * Tc + rc];
    sW[tid] = wList[e * Tc + rc];
  }

  const int ar = tid >> 2;
  const int ak = (tid & 3) * 8;
  int arow = m0 + ar;
  if (arow >= M) arow = M - 1;
  const size_t abase = (size_t)(off[e] + arow) * Ic + ak;
  const unsigned short* aph = actH + abase;
  const unsigned short* apl = actL + abase;

  const size_t bbase = ((size_t)e * Hc + n0 + ar) * Ic + ak;
  const unsigned short* bph = dwTh + bbase;
  const unsigned short* bpl = dwTl + bbase;

  f32x4 acc[4];
#pragma unroll
  for (int i = 0; i < 4; ++i) acc[i] = f32x4{0.f, 0.f, 0.f, 0.f};

  const int lane = tid & 63;
  const int wv = tid >> 6;
  const int q = lane >> 4;
  const int mr = lane & 15;
  const int nc = wv * 16 + (lane & 15);

  for (int k0 = 0; k0 < Ic; k0 += 32) {
    __syncthreads();
    *(uint4*)&sAh[ar][ak] = *(const uint4*)(aph + k0);
    *(uint4*)&sBh[ar][ak] = *(const uint4*)(bph + k0);
    if constexpr (SPLIT) {
      *(uint4*)&sAl[ar][ak] = *(const uint4*)(apl + k0);
      *(uint4*)&sBl[ar][ak] = *(const uint4*)(bpl + k0);
    }
    __syncthreads();

    bf16x8 a_h[4], a_l[4];
#pragma unroll
    for (int mt = 0; mt < 4; ++mt) {
      a_h[mt] = ldfrag(&sAh[mt * 16 + mr][q * 8]);
      if constexpr (SPLIT) a_l[mt] = ldfrag(&sAl[mt * 16 + mr][q * 8]);
    }
    const bf16x8 b_h = ldfrag(&sBh[nc][q * 8]);
    bf16x8 b_l;
    if constexpr (SPLIT) b_l = ldfrag(&sBl[nc][q * 8]);
#pragma unroll
    for (int mt = 0; mt < 4; ++mt) {
      acc[mt] = __builtin_amdgcn_mfma_f32_16x16x32_bf16(a_h[mt], b_h, acc[mt], 0, 0, 0);
      if constexpr (SPLIT) {
        acc[mt] = __builtin_amdgcn_mfma_f32_16x16x32_bf16(a_h[mt], b_l, acc[mt], 0, 0, 0);
        acc[mt] = __builtin_amdgcn_mfma_f32_16x16x32_bf16(a_l[mt], b_h, acc[mt], 0, 0, 0);
      }
    }
  }

  const int valid = M - m0;
#pragma unroll
  for (int mt = 0; mt < 4; ++mt) {
#pragma unroll
    for (int r = 0; r < 4; ++r) {
      const int row = mt * 16 + q * 4 + r;
      if (row < valid) {
        atomicAdd(&out[(size_t)sTok[row] * Hc + (n0 + nc)], sW[row] * acc[mt][r]);
      }
    }
  }
}

// ---------------- host ----------------
extern "C" void kernel_launch(void* const* d_in, const int* in_sizes, int n_in, void* d_out,
                              int out_size, void* d_ws, size_t ws_size, hipStream_t stream) {
  const float* x_in = (const float*)d_in[0];
  const float* rw = (const float*)d_in[1];
  const float* guw = (const float*)d_in[2];
  const float* dnw = (const float*)d_in[3];
  float* out = (float*)d_out;
  float* logits_base = out + (size_t)Tc * Hc;

  uint8_t* w = (uint8_t*)d_ws;
  float* x1 = (float*)w;                    w += (size_t)Tc * Hc * 4;
  unsigned short* xh = (unsigned short*)w;  w += (size_t)Tc * Hc * 2;
  unsigned short* xl = (unsigned short*)w;  w += (size_t)Tc * Hc * 2;
  unsigned short* actH = (unsigned short*)w; w += (size_t)Tc * 2 * Ic * 2;
  unsigned short* actL = (unsigned short*)w; w += (size_t)Tc * 2 * Ic * 2;
  int* tokList = (int*)w;                   w += (size_t)Ec * Tc * 4;
  float* wList = (float*)w;                 w += (size_t)Ec * Tc * 4;
  int* cnt0 = (int*)w;                      w += 64;
  int* cnt1 = (int*)w;                      w += 64;
  int* off = (int*)w;                       w += 64;
  // weight scratch: hi/lo each sized for the larger (gate_up) tensor; reused for down
  unsigned short* wTh = (unsigned short*)w; w += (size_t)Ec * 2 * Ic * Hc * 2;
  unsigned short* wTl = (unsigned short*)w; w += (size_t)Ec * 2 * Ic * Hc * 2;

  hipMemsetAsync(cnt0, 0, 192, stream);                  // cnt0, cnt1, off
  hipMemsetAsync(x1, 0, (size_t)Tc * Hc * 4, stream);    // layer-0 scatter target
  hipMemsetAsync(out, 0, (size_t)Tc * Hc * 4, stream);   // final x section

  // ---- layer 0 (split-bf16 precision; protects layer-1 routing) ----
  router_kernel<<<Tc, 256, 0, stream>>>(x_in, rw, logits_base);
  topk_kernel<<<Tc / 256, 256, 0, stream>>>(logits_base, cnt0, tokList, wList);
  offsets_kernel<<<1, 64, 0, stream>>>(cnt0, off);
  convert_kernel<<<(Tc * Hc) / 256, 256, 0, stream>>>(x_in, xh, xl);
  // transpose+convert gate_up weights: [E][H][2I] fp32 -> [E][2I][H] bf16 hi/lo
  wconv_kernel<true><<<dim3(2 * Ic / 64, Hc / 64, Ec), 256, 0, stream>>>(guw, wTh, wTl, Hc, 2 * Ic);
  gateup_kernel<true><<<dim3(32, Ic / 64, Ec), 256, 0, stream>>>(xh, xl, wTh, wTl, cnt0, off,
                                                                 tokList, actH, actL);
  // transpose+convert down weights into the SAME scratch (stream-ordered after gateup)
  wconv_kernel<true><<<dim3(Hc / 64, Ic / 64, Ec), 256, 0, stream>>>(dnw, wTh, wTl, Ic, Hc);
  down_kernel<true><<<dim3(32, Hc / 64, Ec), 256, 0, stream>>>(actH, actL, wTh, wTl, cnt0, off,
                                                               tokList, wList, x1);

  // ---- layer 1 (plain bf16) ----
  const float* rw1 = rw + (size_t)Hc * Ec;
  const float* guw1 = guw + (size_t)Ec * Hc * 2 * Ic;
  const float* dnw1 = dnw + (size_t)Ec * Ic * Hc;
  router_kernel<<<Tc, 256, 0, stream>>>(x1, rw1, logits_base + (size_t)Tc * Ec);
  topk_kernel<<<Tc / 256, 256, 0, stream>>>(logits_base + (size_t)Tc * Ec, cnt1, tokList, wList);
  offsets_kernel<<<1, 64, 0, stream>>>(cnt1, off);
  convert_kernel<<<(Tc * Hc) / 256, 256, 0, stream>>>(x1, xh, xl);
  wconv_kernel<false><<<dim3(2 * Ic / 64, Hc / 64, Ec), 256, 0, stream>>>(guw1, wTh, wTl, Hc, 2 * Ic);
  gateup_kernel<false><<<dim3(32, Ic / 64, Ec), 256, 0, stream>>>(xh, xl, wTh, wTl, cnt1, off,
                                                                  tokList, actH, actL);
  wconv_kernel<false><<<dim3(Hc / 64, Ic / 64, Ec), 256, 0, stream>>>(dnw1, wTh, wTl, Ic, Hc);
  down_kernel<false><<<dim3(32, Hc / 64, Ec), 256, 0, stream>>>(actH, actL, wTh, wTl, cnt1, off,
                                                                tokList, wList, out);
}